// Round 2
// baseline (627.168 us; speedup 1.0000x reference)
//
#include <hip/hip_runtime.h>
#include <hip/hip_bf16.h>

// Attention fwd: B=4 H=16 S=2048 D=128, fp32 in/out, scale = 128^-0.5.
// R2: XOR-swizzled unpadded LDS tiles (48 KB -> 3 blocks/CU, was 62.5 KB -> 2),
// P overlaid on K tile (extra barrier after QK reads; P reads are wave-private),
// K preconverted to bf16 in d_ws (guarded on ws_size) so per-iter staging is
// pure uint4 copies. Flash attention, mfma_f32_16x16x32_bf16, 4 waves/block,
// 64 Q rows/block (16/wave), 64-key KV tiles.

#define SEQ 2048
#define DH  128
#define NBH 64
#define BM  64
#define BN  64

typedef __attribute__((ext_vector_type(8))) short short8;
typedef __attribute__((ext_vector_type(4))) float f32x4;

#if __has_builtin(__builtin_amdgcn_exp2f)
#define EXP2F(x) __builtin_amdgcn_exp2f(x)
#else
#define EXP2F(x) exp2f(x)
#endif

// softmax scale folded with log2(e): exp(s*scale) == exp2(s*CS)
#define CS (0.08838834764831845f * 1.44269504088896340736f)

__device__ __forceinline__ unsigned int f2bf(float f) {
    union { float f; unsigned int u; } cv;
    cv.f = f;
    unsigned int u = cv.u;
    return (u + 0x7FFFu + ((u >> 16) & 1u)) >> 16;   // RNE bf16
}

// Swizzled LDS offsets (in shorts). 16B chunks, bank period = 8 chunks.
// Q/K tiles: 64 rows x 128 shorts (16 chunks/row)
__device__ __forceinline__ int qk_off(int row, int chunk) {
    int swz = (chunk & 8) | ((chunk ^ row) & 7);
    return row * 128 + swz * 8;
}
// V tile: 128 rows x 64 shorts (8 chunks/row)
__device__ __forceinline__ int v_off(int row, int chunk) {
    return row * 64 + ((chunk ^ row) & 7) * 8;
}
// P tile (overlaid on K region): 64 rows x 64 shorts
__device__ __forceinline__ int p_off(int row, int chunk) {
    return row * 64 + ((chunk ^ row) & 7) * 8;
}

// ---- V transpose + bf16 convert: V[bh][s][d] (f32) -> VT[bh][d][s] (bf16) ----
__global__ __launch_bounds__(256) void transpose_v_kernel(
        const float* __restrict__ v, unsigned short* __restrict__ vt) {
    __shared__ float tile[64][65];
    const int bh = blockIdx.z;
    const int s0 = blockIdx.x * 64;
    const int d0 = blockIdx.y * 64;
    const int tid = threadIdx.x;
    const float* src = v + ((size_t)bh * SEQ + s0) * DH + d0;
#pragma unroll
    for (int i = 0; i < 4; ++i) {
        int id  = tid + 256 * i;
        int row = id >> 4;
        int c4  = (id & 15) << 2;
        float4 val = *reinterpret_cast<const float4*>(src + row * DH + c4);
        tile[row][c4 + 0] = val.x;
        tile[row][c4 + 1] = val.y;
        tile[row][c4 + 2] = val.z;
        tile[row][c4 + 3] = val.w;
    }
    __syncthreads();
    unsigned short* dst = vt + ((size_t)bh * DH + d0) * SEQ + s0;
#pragma unroll
    for (int i = 0; i < 2; ++i) {
        int id = tid + 256 * i;
        int dd = id >> 3;
        int kc = (id & 7) << 3;
        uint4 pk;
        unsigned int* pw = reinterpret_cast<unsigned int*>(&pk);
#pragma unroll
        for (int j = 0; j < 4; ++j) {
            unsigned int lo = f2bf(tile[kc + 2 * j    ][dd]);
            unsigned int hi = f2bf(tile[kc + 2 * j + 1][dd]);
            pw[j] = lo | (hi << 16);
        }
        *reinterpret_cast<uint4*>(dst + (size_t)dd * SEQ + kc) = pk;
    }
}

// ---- flat fp32 -> bf16 convert (for K) ----
__global__ __launch_bounds__(256) void convert_bf16_kernel(
        const float* __restrict__ x, unsigned short* __restrict__ y) {
    size_t i = ((size_t)blockIdx.x * 256 + threadIdx.x) * 8;
    float4 a = *reinterpret_cast<const float4*>(x + i);
    float4 b = *reinterpret_cast<const float4*>(x + i + 4);
    uint4 pk;
    pk.x = f2bf(a.x) | (f2bf(a.y) << 16);
    pk.y = f2bf(a.z) | (f2bf(a.w) << 16);
    pk.z = f2bf(b.x) | (f2bf(b.y) << 16);
    pk.w = f2bf(b.z) | (f2bf(b.w) << 16);
    *reinterpret_cast<uint4*>(y + i) = pk;
}

// ---- flash attention ----
template <bool KBF16>
__global__ __launch_bounds__(256) void fattn_kernel(
        const float* __restrict__ q, const float* __restrict__ k,
        const unsigned short* __restrict__ kt,
        const unsigned short* __restrict__ vt, float* __restrict__ out) {
    __shared__ unsigned short Qs[BM * DH];     // 16 KB, swizzled
    __shared__ unsigned short KPs[BN * DH];    // 16 KB, K tile; P overlaid post-QK
    __shared__ unsigned short Vs[DH * BN];     // 16 KB, transposed V tile

    const int bh   = blockIdx.y;
    const int q0   = blockIdx.x * BM;
    const int tid  = threadIdx.x;
    const int w    = tid >> 6;
    const int lane = tid & 63;
    const int l15  = lane & 15;
    const int quad = lane >> 4;

    // ---- stage Q tile (64 x 128), f32 -> bf16, once ----
    const float* qbase = q + ((size_t)bh * SEQ + q0) * DH;
#pragma unroll
    for (int i = 0; i < 4; ++i) {
        int id  = tid + 256 * i;
        int row = id >> 4;
        int ch  = id & 15;
        const float* src = qbase + (size_t)row * DH + ch * 8;
        float4 a = *reinterpret_cast<const float4*>(src);
        float4 b = *reinterpret_cast<const float4*>(src + 4);
        uint4 pk;
        pk.x = f2bf(a.x) | (f2bf(a.y) << 16);
        pk.y = f2bf(a.z) | (f2bf(a.w) << 16);
        pk.z = f2bf(b.x) | (f2bf(b.y) << 16);
        pk.w = f2bf(b.z) | (f2bf(b.w) << 16);
        *reinterpret_cast<uint4*>(&Qs[qk_off(row, ch)]) = pk;
    }

    f32x4 o[8];
#pragma unroll
    for (int t = 0; t < 8; ++t) o[t] = (f32x4){0.f, 0.f, 0.f, 0.f};
    float mrow[4] = {-1e30f, -1e30f, -1e30f, -1e30f};
    float lrow[4] = {0.f, 0.f, 0.f, 0.f};

    const float*          kbase  = k  + (size_t)bh * SEQ * DH;
    const unsigned short* ktbase = kt + (size_t)bh * SEQ * DH;
    const unsigned short* vbase  = vt + (size_t)bh * DH * SEQ;

    for (int kt_i = 0; kt_i < SEQ / BN; ++kt_i) {
        const int k0 = kt_i * BN;
        // ---- stage K tile (64 keys x 128 d) ----
        if (KBF16) {
#pragma unroll
            for (int i = 0; i < 4; ++i) {
                int id  = tid + 256 * i;
                int row = id >> 4;
                int ch  = id & 15;
                uint4 val = *reinterpret_cast<const uint4*>(
                    ktbase + (size_t)(k0 + row) * DH + ch * 8);
                *reinterpret_cast<uint4*>(&KPs[qk_off(row, ch)]) = val;
            }
        } else {
#pragma unroll
            for (int i = 0; i < 4; ++i) {
                int id  = tid + 256 * i;
                int row = id >> 4;
                int ch  = id & 15;
                const float* src = kbase + (size_t)(k0 + row) * DH + ch * 8;
                float4 a = *reinterpret_cast<const float4*>(src);
                float4 b = *reinterpret_cast<const float4*>(src + 4);
                uint4 pk;
                pk.x = f2bf(a.x) | (f2bf(a.y) << 16);
                pk.y = f2bf(a.z) | (f2bf(a.w) << 16);
                pk.z = f2bf(b.x) | (f2bf(b.y) << 16);
                pk.w = f2bf(b.z) | (f2bf(b.w) << 16);
                *reinterpret_cast<uint4*>(&KPs[qk_off(row, ch)]) = pk;
            }
        }
        // ---- stage VT tile (128 d x 64 keys), already bf16 ----
#pragma unroll
        for (int i = 0; i < 4; ++i) {
            int id = tid + 256 * i;
            int dd = id >> 3;
            int ch = id & 7;
            uint4 val = *reinterpret_cast<const uint4*>(
                vbase + (size_t)dd * SEQ + k0 + ch * 8);
            *reinterpret_cast<uint4*>(&Vs[v_off(dd, ch)]) = val;
        }
        __syncthreads();   // bar1: tiles staged

        // ---- S = Q K^T : wave w computes rows [w*16, w*16+16) x 64 keys ----
        f32x4 acc[4];
#pragma unroll
        for (int t = 0; t < 4; ++t) acc[t] = (f32x4){0.f, 0.f, 0.f, 0.f};
#pragma unroll
        for (int kk = 0; kk < 4; ++kk) {
            const int ch = kk * 4 + quad;
            short8 a = *reinterpret_cast<const short8*>(&Qs[qk_off(w * 16 + l15, ch)]);
#pragma unroll
            for (int t = 0; t < 4; ++t) {
                short8 b = *reinterpret_cast<const short8*>(&KPs[qk_off(t * 16 + l15, ch)]);
                acc[t] = __builtin_amdgcn_mfma_f32_16x16x32_bf16(a, b, acc[t], 0, 0, 0);
            }
        }
        __syncthreads();   // bar2: all QK reads of K done; P may overwrite K region

        // ---- online softmax (exp2 domain); row = w*16 + quad*4 + r ----
#pragma unroll
        for (int r = 0; r < 4; ++r) {
            float mx = fmaxf(fmaxf(acc[0][r], acc[1][r]), fmaxf(acc[2][r], acc[3][r]));
#pragma unroll
            for (int off = 1; off < 16; off <<= 1)
                mx = fmaxf(mx, __shfl_xor(mx, off));
            float mnew  = fmaxf(mrow[r], CS * mx);
            float alpha = EXP2F(mrow[r] - mnew);
            mrow[r] = mnew;
            float p[4];
            float ps = 0.f;
#pragma unroll
            for (int t = 0; t < 4; ++t) {
                p[t] = EXP2F(CS * acc[t][r] - mnew);
                ps += p[t];
            }
#pragma unroll
            for (int off = 1; off < 16; off <<= 1)
                ps += __shfl_xor(ps, off);
            lrow[r] = lrow[r] * alpha + ps;
#pragma unroll
            for (int t = 0; t < 8; ++t) o[t][r] *= alpha;
            const int prow = w * 16 + quad * 4 + r;
#pragma unroll
            for (int t = 0; t < 4; ++t) {
                int key = t * 16 + l15;
                KPs[prow * 64 + (((key >> 3) ^ (prow & 7)) & 7) * 8 + (key & 7)] =
                    (unsigned short)f2bf(p[t]);
            }
        }

        // ---- O += P V : A-frag from own P rows (wave-private, no barrier) ----
#pragma unroll
        for (int kk = 0; kk < 2; ++kk) {
            const int ch = kk * 4 + quad;
            short8 a = *reinterpret_cast<const short8*>(&KPs[p_off(w * 16 + l15, ch)]);
#pragma unroll
            for (int t = 0; t < 8; ++t) {
                short8 b = *reinterpret_cast<const short8*>(&Vs[v_off(t * 16 + l15, ch)]);
                o[t] = __builtin_amdgcn_mfma_f32_16x16x32_bf16(a, b, o[t], 0, 0, 0);
            }
        }
        __syncthreads();   // bar3: PV reads done before next iteration's staging
    }

    // ---- epilogue: normalize and store fp32 ----
    float* obase = out + ((size_t)bh * SEQ + q0) * DH;
#pragma unroll
    for (int r = 0; r < 4; ++r) {
        float inv = 1.0f / lrow[r];
        int row = w * 16 + quad * 4 + r;
#pragma unroll
        for (int t = 0; t < 8; ++t)
            obase[(size_t)row * DH + t * 16 + l15] = o[t][r] * inv;
    }
}

extern "C" void kernel_launch(void* const* d_in, const int* in_sizes, int n_in,
                              void* d_out, int out_size, void* d_ws, size_t ws_size,
                              hipStream_t stream) {
    const float* q = (const float*)d_in[0];
    const float* k = (const float*)d_in[1];
    const float* v = (const float*)d_in[2];
    float* out = (float*)d_out;
    const size_t n_elem = (size_t)NBH * SEQ * DH;          // 16.78M
    unsigned short* vt = (unsigned short*)d_ws;            // 32 MB
    unsigned short* kt = vt + n_elem;                      // +32 MB
    const bool kbf = ws_size >= 2 * n_elem * sizeof(unsigned short);

    transpose_v_kernel<<<dim3(SEQ / 64, DH / 64, NBH), dim3(256), 0, stream>>>(v, vt);
    if (kbf) {
        convert_bf16_kernel<<<dim3((unsigned)(n_elem / (256 * 8))), dim3(256), 0, stream>>>(k, kt);
        fattn_kernel<true><<<dim3(SEQ / BM, NBH), dim3(256), 0, stream>>>(q, k, kt, vt, out);
    } else {
        fattn_kernel<false><<<dim3(SEQ / BM, NBH), dim3(256), 0, stream>>>(q, k, kt, vt, out);
    }
}